// Round 3
// baseline (845.432 us; speedup 1.0000x reference)
//
#include <hip/hip_runtime.h>
#include <stdint.h>

#define EPS 1e-5f

typedef __attribute__((ext_vector_type(8))) short bf16x8;
typedef __attribute__((ext_vector_type(4))) float f32x4;

__device__ __forceinline__ short f2bf(float f) {
  union { float f; unsigned u; } c; c.f = f;
  unsigned r = (c.u + 0x7FFFu + ((c.u >> 16) & 1u)) >> 16;
  return (short)r;
}
__device__ __forceinline__ float bf2f(unsigned short s) {
  union { unsigned u; float f; } c; c.u = ((unsigned)s) << 16;
  return c.f;
}

// ws float-offset layout
#define WS_SUM1 0
#define WS_SQ1  256
#define WS_SUM2 512
#define WS_SQ2  576
#define WS_M1   640
#define WS_I1   896
#define WS_M2   1152
#define WS_I2   1216
#define H2S_BYTE_OFF 8192

__global__ void k_zero(float* ws) {
  for (int i = threadIdx.x; i < 640; i += 256) ws[i] = 0.f;
}

__global__ void k_finalize(float* ws, int n, int so, int qo, int mo, int io, float invE) {
  int j = threadIdx.x;
  if (j < n) {
    float m = ws[so + j] * invE;
    float var = ws[qo + j] * invE - m * m;
    ws[mo + j] = m;
    ws[io + j] = rsqrtf(var + EPS);
  }
}

// MODE 0: GEMM1 -> stats1.  MODE 1: GEMM1+norm+GEMM2 -> stats2 (+optional h2 store).
// MODE 2: full recompute -> out (fallback when ws too small for h2 store).
template <int MODE>
__global__ __launch_bounds__(256, 2) void fused_pass(
    const float* __restrict__ emb, const int* __restrict__ ei,
    const float* __restrict__ W1, const float* __restrict__ b1,
    const float* __restrict__ W2, const float* __restrict__ b2,
    const float* __restrict__ W3, const float* __restrict__ b3,
    float* __restrict__ ws, unsigned short* __restrict__ h2s,
    float* __restrict__ out, int E, int storeH2) {
  extern __shared__ __align__(16) char lds[];
  // A tile [64][128] bf16 swizzled: bytes [0, 16384)
  // g tile [64][256] bf16 swizzled: bytes [16384, 49152)  (MODE >= 1)
  // outp float[64] at 49152                               (MODE == 2)
  const int tid = threadIdx.x;
  const int lane = tid & 63;
  const int w = tid >> 6;   // wave 0..3
  const int l15 = lane & 15;
  const int l4 = lane >> 4; // 0..3

  // ---- persistent B1 fragments: wave w owns h1 columns [64w, 64w+64)
  bf16x8 B1[4][4]; // [ni][kk]
#pragma unroll
  for (int ni = 0; ni < 4; ++ni)
#pragma unroll
    for (int kk = 0; kk < 4; ++kk) {
      const int c = w * 64 + ni * 16 + l15;
      const int kb = kk * 32 + l4 * 8;
      bf16x8 v;
#pragma unroll
      for (int i = 0; i < 8; ++i) v[i] = f2bf(W1[(kb + i) * 256 + c]);
      B1[ni][kk] = v;
    }
  float b1v[4], m1v[4] = {0, 0, 0, 0}, i1v[4] = {0, 0, 0, 0};
#pragma unroll
  for (int ni = 0; ni < 4; ++ni) {
    const int c = w * 64 + ni * 16 + l15;
    b1v[ni] = b1[c];
    if (MODE >= 1) { m1v[ni] = ws[WS_M1 + c]; i1v[ni] = ws[WS_I1 + c]; }
  }
  bf16x8 B2[8];
  float b2v = 0.f, m2v = 0.f, i2v = 0.f, w3v = 0.f;
  if (MODE >= 1) {
#pragma unroll
    for (int kk = 0; kk < 8; ++kk) {
      const int c = w * 16 + l15;
      const int kb = kk * 32 + l4 * 8;
      bf16x8 v;
#pragma unroll
      for (int i = 0; i < 8; ++i) v[i] = f2bf(W2[(kb + i) * 64 + c]);
      B2[kk] = v;
    }
    b2v = b2[w * 16 + l15];
    if (MODE == 2) {
      m2v = ws[WS_M2 + w * 16 + l15];
      i2v = ws[WS_I2 + w * 16 + l15];
      w3v = W3[w * 16 + l15];
    }
  }

  float sAcc[4] = {0, 0, 0, 0}, qAcc[4] = {0, 0, 0, 0}; // MODE0 stats1
  float s2A = 0.f, q2A = 0.f;                           // MODE1 stats2

  const int nTiles = E >> 6;
  for (int t = blockIdx.x; t < nTiles; t += gridDim.x) {
    const int e0 = t << 6;
    __syncthreads(); // protect A/g/outp reuse across iterations

    // ---- stage A tile: thread -> (edge e = tid>>2, 32-col chunk q = tid&3)
    {
      const int e = tid >> 2, q = tid & 3;
      const int nidx = (q < 2) ? ei[e0 + e] : ei[E + e0 + e];
      const float* src = emb + (long)nidx * 64 + (q & 1) * 32;
#pragma unroll
      for (int jj = 0; jj < 4; ++jj) {
        float4 fa = *reinterpret_cast<const float4*>(src + jj * 8);
        float4 fb = *reinterpret_cast<const float4*>(src + jj * 8 + 4);
        bf16x8 p;
        p[0] = f2bf(fa.x); p[1] = f2bf(fa.y); p[2] = f2bf(fa.z); p[3] = f2bf(fa.w);
        p[4] = f2bf(fb.x); p[5] = f2bf(fb.y); p[6] = f2bf(fb.z); p[7] = f2bf(fb.w);
        int byte = e * 256 + q * 64 + jj * 16;
        byte ^= (e & 7) << 4;
        *reinterpret_cast<bf16x8*>(lds + byte) = p;
      }
      if (MODE == 2) {
        if (tid < 64) reinterpret_cast<float*>(lds + 49152)[tid] = 0.f;
      }
    }
    __syncthreads();

    // ---- GEMM1: wave tile 64 rows x 64 cols
    f32x4 acc[4][4];
#pragma unroll
    for (int mi = 0; mi < 4; ++mi)
#pragma unroll
      for (int ni = 0; ni < 4; ++ni) acc[mi][ni] = f32x4{0.f, 0.f, 0.f, 0.f};
#pragma unroll
    for (int kk = 0; kk < 4; ++kk) {
      bf16x8 af[4];
#pragma unroll
      for (int mi = 0; mi < 4; ++mi) {
        const int row = mi * 16 + l15;
        int byte = row * 256 + kk * 64 + l4 * 16;
        byte ^= (row & 7) << 4;
        af[mi] = *reinterpret_cast<const bf16x8*>(lds + byte);
      }
#pragma unroll
      for (int ni = 0; ni < 4; ++ni)
#pragma unroll
        for (int mi = 0; mi < 4; ++mi)
          acc[mi][ni] = __builtin_amdgcn_mfma_f32_16x16x32_bf16(af[mi], B1[ni][kk], acc[mi][ni], 0, 0, 0);
    }

    if (MODE == 0) {
#pragma unroll
      for (int mi = 0; mi < 4; ++mi)
#pragma unroll
        for (int ni = 0; ni < 4; ++ni)
#pragma unroll
          for (int r = 0; r < 4; ++r) {
            const float v = acc[mi][ni][r] + b1v[ni];
            sAcc[ni] += v;
            qAcc[ni] += v * v;
          }
    } else {
      // ---- normalize + relu -> g tile (bf16, swizzled)
      char* g = lds + 16384;
#pragma unroll
      for (int mi = 0; mi < 4; ++mi)
#pragma unroll
        for (int ni = 0; ni < 4; ++ni) {
          const int c = w * 64 + ni * 16 + l15;
#pragma unroll
          for (int r = 0; r < 4; ++r) {
            const int row = mi * 16 + l4 * 4 + r;
            float v = (acc[mi][ni][r] + b1v[ni] - m1v[ni]) * i1v[ni];
            v = v > 0.f ? v : 0.f;
            int byte = row * 512 + c * 2;
            byte ^= (row & 7) << 4;
            *reinterpret_cast<short*>(g + byte) = f2bf(v);
          }
        }
      __syncthreads();

      // ---- GEMM2: wave tile 64 rows x 16 cols, K=256
      f32x4 acc2[4];
#pragma unroll
      for (int mi = 0; mi < 4; ++mi) acc2[mi] = f32x4{0.f, 0.f, 0.f, 0.f};
#pragma unroll
      for (int kk = 0; kk < 8; ++kk) {
#pragma unroll
        for (int mi = 0; mi < 4; ++mi) {
          const int row = mi * 16 + l15;
          int byte = row * 512 + kk * 64 + l4 * 16;
          byte ^= (row & 7) << 4;
          const bf16x8 a2 = *reinterpret_cast<const bf16x8*>(g + byte);
          acc2[mi] = __builtin_amdgcn_mfma_f32_16x16x32_bf16(a2, B2[kk], acc2[mi], 0, 0, 0);
        }
      }

      if (MODE == 1) {
#pragma unroll
        for (int mi = 0; mi < 4; ++mi)
#pragma unroll
          for (int r = 0; r < 4; ++r) {
            const float v = acc2[mi][r] + b2v;
            s2A += v;
            q2A += v * v;
            if (storeH2) {
              const int row = e0 + mi * 16 + l4 * 4 + r;
              h2s[(size_t)row * 64 + w * 16 + l15] = (unsigned short)f2bf(v);
            }
          }
      } else { // MODE 2: final output
        float* outp = reinterpret_cast<float*>(lds + 49152);
#pragma unroll
        for (int mi = 0; mi < 4; ++mi)
#pragma unroll
          for (int r = 0; r < 4; ++r) {
            const float v = acc2[mi][r] + b2v;
            float z = (v - m2v) * i2v;
            z = z > 0.f ? z : 0.f;
            float pv = z * w3v;
            pv += __shfl_xor(pv, 1);
            pv += __shfl_xor(pv, 2);
            pv += __shfl_xor(pv, 4);
            pv += __shfl_xor(pv, 8);
            if (l15 == 0) atomicAdd(&outp[mi * 16 + l4 * 4 + r], pv);
          }
        __syncthreads();
        if (tid < 64) out[e0 + tid] = outp[tid] + b3[0];
      }
    }
  }

  // ---- flush stats
  if (MODE == 0) {
#pragma unroll
    for (int ni = 0; ni < 4; ++ni) {
      float s = sAcc[ni], q = qAcc[ni];
      s += __shfl_xor(s, 16); s += __shfl_xor(s, 32);
      q += __shfl_xor(q, 16); q += __shfl_xor(q, 32);
      if (lane < 16) {
        atomicAdd(&ws[WS_SUM1 + w * 64 + ni * 16 + lane], s);
        atomicAdd(&ws[WS_SQ1 + w * 64 + ni * 16 + lane], q);
      }
    }
  }
  if (MODE == 1) {
    float s = s2A, q = q2A;
    s += __shfl_xor(s, 16); s += __shfl_xor(s, 32);
    q += __shfl_xor(q, 16); q += __shfl_xor(q, 32);
    if (lane < 16) {
      atomicAdd(&ws[WS_SUM2 + w * 16 + lane], s);
      atomicAdd(&ws[WS_SQ2 + w * 16 + lane], q);
    }
  }
}

// epilogue from stored h2 (bf16): norm2 + relu + dot(W3) + b3
__global__ void k_out(const unsigned short* __restrict__ h2s, const float* __restrict__ ws,
                      const float* __restrict__ W3, const float* __restrict__ b3,
                      float* __restrict__ out, int E) {
  __shared__ float sm[64], si[64], sw[64];
  const int tid = threadIdx.x;
  if (tid < 64) {
    sm[tid] = ws[WS_M2 + tid];
    si[tid] = ws[WS_I2 + tid];
    sw[tid] = W3[tid];
  }
  __syncthreads();
  const int e = blockIdx.x * 256 + tid;
  if (e >= E) return;
  const unsigned short* rp = h2s + (size_t)e * 64;
  float a = 0.f;
#pragma unroll
  for (int jj = 0; jj < 8; ++jj) {
    const bf16x8 v8 = *reinterpret_cast<const bf16x8*>(rp + jj * 8);
#pragma unroll
    for (int i = 0; i < 8; ++i) {
      const int j = jj * 8 + i;
      const float v = bf2f((unsigned short)v8[i]);
      float z = (v - sm[j]) * si[j];
      z = z > 0.f ? z : 0.f;
      a += z * sw[j];
    }
  }
  out[e] = a + b3[0];
}

extern "C" void kernel_launch(void* const* d_in, const int* in_sizes, int n_in,
                              void* d_out, int out_size, void* d_ws, size_t ws_size,
                              hipStream_t stream) {
  (void)n_in; (void)out_size;
  const float* emb = (const float*)d_in[0];
  const int* ei = (const int*)d_in[1];
  const float* W1 = (const float*)d_in[2];
  const float* b1 = (const float*)d_in[3];
  const float* W2 = (const float*)d_in[4];
  const float* b2 = (const float*)d_in[5];
  const float* W3 = (const float*)d_in[6];
  const float* b3 = (const float*)d_in[7];
  float* out = (float*)d_out;
  float* ws = (float*)d_ws;
  unsigned short* h2s = (unsigned short*)((char*)d_ws + H2S_BYTE_OFF);

  const int E = in_sizes[1] / 2;
  const int storeH2 = (ws_size >= (size_t)H2S_BYTE_OFF + (size_t)E * 64 * 2) ? 1 : 0;
  const float invE = 1.0f / (float)E;

  k_zero<<<1, 256, 0, stream>>>(ws);
  fused_pass<0><<<768, 256, 16384, stream>>>(emb, ei, W1, b1, W2, b2, W3, b3, ws, h2s, out, E, storeH2);
  k_finalize<<<1, 256, 0, stream>>>(ws, 256, WS_SUM1, WS_SQ1, WS_M1, WS_I1, invE);
  fused_pass<1><<<512, 256, 49152, stream>>>(emb, ei, W1, b1, W2, b2, W3, b3, ws, h2s, out, E, storeH2);
  k_finalize<<<1, 256, 0, stream>>>(ws, 64, WS_SUM2, WS_SQ2, WS_M2, WS_I2, invE);
  if (storeH2) {
    k_out<<<(E + 255) / 256, 256, 0, stream>>>(h2s, ws, W3, b3, out, E);
  } else {
    fused_pass<2><<<512, 256, 49152 + 256, stream>>>(emb, ei, W1, b1, W2, b2, W3, b3, ws, h2s, out, E, storeH2);
  }
}